// Round 1
// 74.057 us; speedup vs baseline: 1.0102x; 1.0102x over previous
//
#include <hip/hip_runtime.h>
#include <math.h>

#define N      128
#define NS     16
#define NC     4
#define NT     4
#define NPIX   (N * N)       // 16384
#define NJC    (N * NC)      // 512 columns (j*4+c)

typedef __attribute__((ext_vector_type(8))) short bf16x8;   // 8 bf16 = 4 VGPR
typedef __attribute__((ext_vector_type(4))) float f32x4;

// float -> bf16 bits, round-to-nearest-even
__device__ __forceinline__ short f2bf(float f) {
    union { float f; unsigned int u; } v; v.f = f;
    unsigned int r = (v.u + 0x7fffu + ((v.u >> 16) & 1u)) >> 16;
    return (short)r;
}

// cis(2*pi*rev) via hardware v_sin_f32/v_cos_f32 (native input: revolutions).
// Range-reduce to [-0.5, 0.5] with rint; no libm sincosf (no Payne-Hanek path,
// no serial polynomial chain).
__device__ __forceinline__ void cis_rev(float rev, float& c, float& s) {
    float f = rev - rintf(rev);
    float ss, cc;
    asm("v_sin_f32 %0, %1" : "=v"(ss) : "v"(f));
    asm("v_cos_f32 %0, %1" : "=v"(cc) : "v"(f));
    s = ss; c = cc;
}

// Pb[t][jc=j*4+c][i] = bf16(csm[c,i,j] * im_t[i,j])  (B-operand layout:
// contiguous in i so a lane's k-chunk is one 16B load). Block 0 zeroes out.
__global__ __launch_bounds__(256) void prep_kernel(
    const float* __restrict__ x, const float* __restrict__ csm,
    const float* __restrict__ flow, short* __restrict__ Pb,
    float* __restrict__ out, int out_size)
{
    int g = blockIdx.x * 256 + threadIdx.x;   // 0 .. NT*NPIX-1
    int t = g >> 14;
    int p = g & (NPIX - 1);
    int i = p >> 7, j = p & (N - 1);
    float f0 = flow[(p * 2 + 0) * NT + t];
    float f1 = flow[(p * 2 + 1) * NT + t];
    int si = (int)rintf((float)i + f0); si = min(max(si, 0), N - 1);
    int sj = (int)rintf((float)j + f1); sj = min(max(sj, 0), N - 1);
    float im = x[si * N + sj];
#pragma unroll
    for (int c = 0; c < NC; ++c) {
        float v = csm[c * NPIX + p] * im;
        Pb[((t * NJC) + j * 4 + c) * N + i] = f2bf(v);
    }
    if (blockIdx.x == 0) {
        for (int k = threadIdx.x; k < out_size; k += 256) out[k] = 0.0f;
    }
}

// MFMA NDFT: S[m,jc] = sum_i Ex[m,i] * P[i,jc] via 16x16x32 bf16 MFMA
// (2 chains: Exr, Exi), then out[m,c] += sum_j Re{Ey[m,j] * S}.
//
// Grid 1024 = (mtile 0..127) x (t 0..3) x (h 0..1). 4 waves/block; each wave
// owns 4 of this half's 16 jc-tiles. 4 blocks/CU resident (launch_bounds 256,4)
// -> 4 waves/SIMD for latency hiding (vs 1 before). eyTab is per-block
// (one t, one j-half): 16 m x 64 j, padded to 66 so the 4 quads' rows land in
// different banks (row stride 132 words, 132%32=4).
__global__ __launch_bounds__(256, 4) void mfma_kernel(
    const float* __restrict__ traj, const short* __restrict__ Pb,
    float* __restrict__ out, int out_size)
{
    __shared__ float eyTab[16][66][2];   // 8.25 KiB

    int b     = blockIdx.x;
    int mtile = b >> 3;            // 0..127
    int t     = (b >> 1) & 3;      // motion state
    int h     = b & 1;             // jc half
    int tid   = threadIdx.x;
    int lane  = tid & 63;
    int w     = tid >> 6;          // wave = tile-group within the half
    int quad  = lane >> 4;
    int l15   = lane & 15;

    const short* PbT = Pb + t * NJC * N;

    // ---- Issue tile-0 B loads FIRST so L2/L3 latency hides under trig setup.
    bf16x8 bpre[4];
    {
        int jc0 = h * 256 + (w * 4) * 16 + l15;
#pragma unroll
        for (int s = 0; s < 4; ++s)
            bpre[s] = *(const bf16x8*)(PbT + jc0 * N + s * 32 + quad * 8);
    }

    // ---- A fragments (in-register): Ex for m = mtile*16 + l15.
    // A layout: A[m = lane&15][k = quad*8 + e], k-step s adds s*32.
    // Direct hw-sin evaluation: no serial recurrence chains.
    int m  = mtile * 16 + l15;
    int sp = m >> 7, r = m & (N - 1);
    float kx = traj[((sp * N + r) * NT + t) * 2 + 0];

    bf16x8 ar[4], ai[4];
#pragma unroll
    for (int s = 0; s < 4; ++s) {
#pragma unroll
        for (int e = 0; e < 8; ++e) {
            float er, ei;
            cis_rev(-kx * (float)(s * 32 + quad * 8 + e - 64), er, ei);
            ar[s][e] = f2bf(er);
            ai[s][e] = f2bf(ei);
        }
    }

    // ---- Ey table (cooperative, 256 threads): ey[m2][j_loc] =
    // cis(-2pi*ky*(j_abs-64)), j_abs = h*64 + j_loc. Direct evaluation.
    {
        int m2  = tid >> 4;                 // 0..15
        int jg  = tid & 15;                 // 0..15
        int mm  = mtile * 16 + m2;
        int sp2 = mm >> 7, r2 = mm & (N - 1);
        float ky = traj[((sp2 * N + r2) * NT + t) * 2 + 1];
#pragma unroll
        for (int u = 0; u < 4; ++u) {
            int j_loc = jg * 4 + u;
            float er, ei;
            cis_rev(-ky * (float)(h * 64 + j_loc - 64), er, ei);
            eyTab[m2][j_loc][0] = er;
            eyTab[m2][j_loc][1] = ei;
        }
    }
    __syncthreads();

    // ---- Main loop: this wave's 4 jc-tiles, prefetch one ahead.
    float partial[4] = {0.f, 0.f, 0.f, 0.f};

#pragma unroll
    for (int it = 0; it < 4; ++it) {
        bf16x8 bcur[4];
#pragma unroll
        for (int s = 0; s < 4; ++s) bcur[s] = bpre[s];
        if (it < 3) {
            int jcn = h * 256 + (w * 4 + it + 1) * 16 + l15;
#pragma unroll
            for (int s = 0; s < 4; ++s)
                bpre[s] = *(const bf16x8*)(PbT + jcn * N + s * 32 + quad * 8);
        }

        f32x4 accR = {0.f, 0.f, 0.f, 0.f};
        f32x4 accI = {0.f, 0.f, 0.f, 0.f};
#pragma unroll
        for (int s = 0; s < 4; ++s) {
            accR = __builtin_amdgcn_mfma_f32_16x16x32_bf16(ar[s], bcur[s], accR, 0, 0, 0);
            accI = __builtin_amdgcn_mfma_f32_16x16x32_bf16(ai[s], bcur[s], accI, 0, 0, 0);
        }

        // C/D layout: col = lane&15 (jc_rel), row = quad*4 + reg (m_rel).
        int j_loc = (w * 4 + it) * 4 + (l15 >> 2);   // 0..63 within this half
#pragma unroll
        for (int reg = 0; reg < 4; ++reg) {
            int mrel = quad * 4 + reg;
            float eyr = eyTab[mrel][j_loc][0];
            float eyi = eyTab[mrel][j_loc][1];
            partial[reg] = fmaf(eyr, accR[reg], partial[reg]);
            partial[reg] = fmaf(-eyi, accI[reg], partial[reg]);
        }
    }

    // ---- Reduce over the 4 j-subgroups (col bits 2,3 = lane bits 2,3).
#pragma unroll
    for (int reg = 0; reg < 4; ++reg) {
        partial[reg] += __shfl_xor(partial[reg], 4, 64);
        partial[reg] += __shfl_xor(partial[reg], 8, 64);
    }
    if ((lane & 12) == 0) {
        int c = lane & 3;
#pragma unroll
        for (int reg = 0; reg < 4; ++reg) {
            int mm  = mtile * 16 + quad * 4 + reg;
            int sp2 = mm >> 7, r2 = mm & (N - 1);
            int q = (r2 * NS + sp2) * NC + c;   // C-order into [1][128][16][4]
            if (q < out_size) atomicAdd(&out[q], partial[reg]);
        }
    }
}

extern "C" void kernel_launch(void* const* d_in, const int* in_sizes, int n_in,
                              void* d_out, int out_size, void* d_ws, size_t ws_size,
                              hipStream_t stream) {
    const float* x    = (const float*)d_in[0];
    const float* traj = (const float*)d_in[1];
    const float* csm  = (const float*)d_in[2];
    // d_in[3] = dcf (unused by the reference)
    const float* flow = (const float*)d_in[4];
    float* out = (float*)d_out;
    short* Pb  = (short*)d_ws;    // NT*512*128 bf16 = 512 KiB

    prep_kernel<<<dim3(NT * NPIX / 256), dim3(256), 0, stream>>>(x, csm, flow, Pb, out, out_size);
    mfma_kernel<<<dim3(128 * NT * 2), dim3(256), 0, stream>>>(traj, Pb, out, out_size);
}

// Round 3
// 73.692 us; speedup vs baseline: 1.0153x; 1.0050x over previous
//
#include <hip/hip_runtime.h>
#include <math.h>

#define N      128
#define NS     16
#define NC     4
#define NT     4
#define NPIX   (N * N)       // 16384
#define NJC    (N * NC)      // 512 columns (j*4+c)

typedef __attribute__((ext_vector_type(8))) short bf16x8;   // 8 bf16 = 4 VGPR
typedef __attribute__((ext_vector_type(4))) float f32x4;

// float -> bf16 bits, round-to-nearest-even
__device__ __forceinline__ short f2bf(float f) {
    union { float f; unsigned int u; } v; v.f = f;
    unsigned int r = (v.u + 0x7fffu + ((v.u >> 16) & 1u)) >> 16;
    return (short)r;
}

// cis(2*pi*rev) via hardware v_sin_f32/v_cos_f32 (native input: revolutions).
// Range-reduce to [-0.5, 0.5] with rint; no libm sincosf (no Payne-Hanek path,
// no serial polynomial chain).
__device__ __forceinline__ void cis_rev(float rev, float& c, float& s) {
    float f = rev - rintf(rev);
    float ss, cc;
    asm("v_sin_f32 %0, %1" : "=v"(ss) : "v"(f));
    asm("v_cos_f32 %0, %1" : "=v"(cc) : "v"(f));
    s = ss; c = cc;
}

// Pb[t][jc=j*4+c][i] = bf16(csm[c,i,j] * im_t[i,j])  (B-operand layout:
// contiguous in i so a lane's k-chunk is one 16B load). Block 0 zeroes out.
__global__ __launch_bounds__(256) void prep_kernel(
    const float* __restrict__ x, const float* __restrict__ csm,
    const float* __restrict__ flow, short* __restrict__ Pb,
    float* __restrict__ out, int out_size)
{
    int g = blockIdx.x * 256 + threadIdx.x;   // 0 .. NT*NPIX-1
    int t = g >> 14;
    int p = g & (NPIX - 1);
    int i = p >> 7, j = p & (N - 1);
    float f0 = flow[(p * 2 + 0) * NT + t];
    float f1 = flow[(p * 2 + 1) * NT + t];
    int si = (int)rintf((float)i + f0); si = min(max(si, 0), N - 1);
    int sj = (int)rintf((float)j + f1); sj = min(max(sj, 0), N - 1);
    float im = x[si * N + sj];
#pragma unroll
    for (int c = 0; c < NC; ++c) {
        float v = csm[c * NPIX + p] * im;
        Pb[((t * NJC) + j * 4 + c) * N + i] = f2bf(v);
    }
    if (blockIdx.x == 0) {
        for (int k = threadIdx.x; k < out_size; k += 256) out[k] = 0.0f;
    }
}

// MFMA NDFT: S[m,jc] = sum_i Ex[m,i] * P[i,jc] via 16x16x32 bf16 MFMA
// (2 chains: Exr, Exi), then out[m,c] += sum_j Re{Ey[m,j] * S}.
//
// Grid 1024 = (mtile 0..127) x (t 0..3) x (h 0..1). 4 waves/block; each wave
// owns 4 of this half's 16 jc-tiles. 4 blocks/CU resident (launch_bounds 256,4)
// -> 4 waves/SIMD for latency hiding. eyTab is per-block (one t, one j-half):
// 16 m x 64 j, padded to 66 so the 4 quads' rows land in different banks.
__global__ __launch_bounds__(256, 4) void mfma_kernel(
    const float* __restrict__ traj, const short* __restrict__ Pb,
    float* __restrict__ out, int out_size)
{
    __shared__ float eyTab[16][66][2];   // 8.25 KiB

    int b     = blockIdx.x;
    int mtile = b >> 3;            // 0..127
    int t     = (b >> 1) & 3;      // motion state
    int h     = b & 1;             // jc half
    int tid   = threadIdx.x;
    int lane  = tid & 63;
    int w     = tid >> 6;          // wave = tile-group within the half
    int quad  = lane >> 4;
    int l15   = lane & 15;

    const short* PbT = Pb + t * NJC * N;

    // ---- Issue tile-0 B loads FIRST so L2/L3 latency hides under trig setup.
    bf16x8 bpre[4];
    {
        int jc0 = h * 256 + (w * 4) * 16 + l15;
#pragma unroll
        for (int s = 0; s < 4; ++s)
            bpre[s] = *(const bf16x8*)(PbT + jc0 * N + s * 32 + quad * 8);
    }

    // ---- A fragments (in-register): Ex for m = mtile*16 + l15.
    // A layout: A[m = lane&15][k = quad*8 + e], k-step s adds s*32.
    int m  = mtile * 16 + l15;
    int sp = m >> 7, r = m & (N - 1);
    float kx = traj[((sp * N + r) * NT + t) * 2 + 0];

    bf16x8 ar[4], ai[4];
#pragma unroll
    for (int s = 0; s < 4; ++s) {
#pragma unroll
        for (int e = 0; e < 8; ++e) {
            float er, ei;
            cis_rev(-kx * (float)(s * 32 + quad * 8 + e - 64), er, ei);
            ar[s][e] = f2bf(er);
            ai[s][e] = f2bf(ei);
        }
    }

    // ---- Ey table (cooperative, 256 threads): ey[m2][j_loc] =
    // cis(-2pi*ky*(j_abs-64)), j_abs = h*64 + j_loc.
    {
        int m2  = tid >> 4;                 // 0..15
        int jg  = tid & 15;                 // 0..15
        int mm  = mtile * 16 + m2;
        int sp2 = mm >> 7, r2 = mm & (N - 1);
        float ky = traj[((sp2 * N + r2) * NT + t) * 2 + 1];
#pragma unroll
        for (int u = 0; u < 4; ++u) {
            int j_loc = jg * 4 + u;
            float er, ei;
            cis_rev(-ky * (float)(h * 64 + j_loc - 64), er, ei);
            eyTab[m2][j_loc][0] = er;
            eyTab[m2][j_loc][1] = ei;
        }
    }
    __syncthreads();

    // ---- Main loop: this wave's 4 jc-tiles, prefetch one ahead.
    float partial[4] = {0.f, 0.f, 0.f, 0.f};

#pragma unroll
    for (int it = 0; it < 4; ++it) {
        bf16x8 bcur[4];
#pragma unroll
        for (int s = 0; s < 4; ++s) bcur[s] = bpre[s];
        if (it < 3) {
            int jcn = h * 256 + (w * 4 + it + 1) * 16 + l15;
#pragma unroll
            for (int s = 0; s < 4; ++s)
                bpre[s] = *(const bf16x8*)(PbT + jcn * N + s * 32 + quad * 8);
        }

        f32x4 accR = {0.f, 0.f, 0.f, 0.f};
        f32x4 accI = {0.f, 0.f, 0.f, 0.f};
#pragma unroll
        for (int s = 0; s < 4; ++s) {
            accR = __builtin_amdgcn_mfma_f32_16x16x32_bf16(ar[s], bcur[s], accR, 0, 0, 0);
            accI = __builtin_amdgcn_mfma_f32_16x16x32_bf16(ai[s], bcur[s], accI, 0, 0, 0);
        }

        // C/D layout: col = lane&15 (jc_rel), row = quad*4 + reg (m_rel).
        int j_loc = (w * 4 + it) * 4 + (l15 >> 2);   // 0..63 within this half
#pragma unroll
        for (int reg = 0; reg < 4; ++reg) {
            int mrel = quad * 4 + reg;
            float eyr = eyTab[mrel][j_loc][0];
            float eyi = eyTab[mrel][j_loc][1];
            partial[reg] = fmaf(eyr, accR[reg], partial[reg]);
            partial[reg] = fmaf(-eyi, accI[reg], partial[reg]);
        }
    }

    // ---- Reduce over the 4 j-subgroups (col bits 2,3 = lane bits 2,3).
#pragma unroll
    for (int reg = 0; reg < 4; ++reg) {
        partial[reg] += __shfl_xor(partial[reg], 4, 64);
        partial[reg] += __shfl_xor(partial[reg], 8, 64);
    }
    if ((lane & 12) == 0) {
        int c = lane & 3;
#pragma unroll
        for (int reg = 0; reg < 4; ++reg) {
            int mm  = mtile * 16 + quad * 4 + reg;
            int sp2 = mm >> 7, r2 = mm & (N - 1);
            int q = (r2 * NS + sp2) * NC + c;   // C-order into [1][128][16][4]
            if (q < out_size) atomicAdd(&out[q], partial[reg]);
        }
    }
}

extern "C" void kernel_launch(void* const* d_in, const int* in_sizes, int n_in,
                              void* d_out, int out_size, void* d_ws, size_t ws_size,
                              hipStream_t stream) {
    const float* x    = (const float*)d_in[0];
    const float* traj = (const float*)d_in[1];
    const float* csm  = (const float*)d_in[2];
    // d_in[3] = dcf (unused by the reference)
    const float* flow = (const float*)d_in[4];
    float* out = (float*)d_out;
    short* Pb  = (short*)d_ws;    // NT*512*128 bf16 = 512 KiB

    prep_kernel<<<dim3(NT * NPIX / 256), dim3(256), 0, stream>>>(x, csm, flow, Pb, out, out_size);
    mfma_kernel<<<dim3(128 * NT * 2), dim3(256), 0, stream>>>(traj, Pb, out, out_size);
}